// Round 1
// baseline (801.230 us; speedup 1.0000x reference)
//
#include <hip/hip_runtime.h>
#include <hip/hip_bf16.h>

// Problem constants (from reference): B=512, K=256, D_MODEL=256, D_INNER=512.
// Key identity: the Hilbert gather/scatter cancels exactly (per-row model),
// so out = slots + LN(SiLU(slots@W1+b1)@W2+b2)*gamma+beta. adj/centroids unused.

#define MROWS (512*256)   // 131072 rows
#define DM 256
#define DI 512

typedef __attribute__((ext_vector_type(8))) short  short8;   // 8 bf16 in 4 VGPRs
typedef __attribute__((ext_vector_type(4))) float  f32x4;

static __device__ __forceinline__ unsigned short f2bf(float f) {
    union { float f; unsigned u; } c; c.f = f;
    unsigned r = c.u + 0x7FFFu + ((c.u >> 16) & 1u);   // RNE
    return (unsigned short)(r >> 16);
}
static __device__ __forceinline__ float bf2f(unsigned short h) {
    union { unsigned u; float f; } c; c.u = ((unsigned)h) << 16;
    return c.f;
}
static __device__ __forceinline__ void split2(float x, unsigned short& hi, unsigned short& lo) {
    hi = f2bf(x);
    lo = f2bf(x - bf2f(hi));   // residual fits easily in bf16 range
}

static __device__ __forceinline__ f32x4 MFMA(short8 a, short8 b, f32x4 c) {
    return __builtin_amdgcn_mfma_f32_16x16x32_bf16(a, b, c, 0, 0, 0);
}

// ---- prep: split weights to hi/lo bf16, transposed k-major for 16B B-frag loads.
// W1 [256][512] -> W1?T [i=512][k=256];  W2 [512][256] -> W2?T [d=256][i=512]
__global__ void gml_prep(const float* __restrict__ W1, const float* __restrict__ W2,
                         unsigned short* __restrict__ W1hT, unsigned short* __restrict__ W1lT,
                         unsigned short* __restrict__ W2hT, unsigned short* __restrict__ W2lT)
{
    int t = blockIdx.x * 256 + threadIdx.x;      // 0 .. 131071
    {
        int i = t >> 8, k = t & 255;
        unsigned short h, l; split2(W1[k * DI + i], h, l);
        W1hT[i * DM + k] = h; W1lT[i * DM + k] = l;
    }
    {
        int d = t >> 9, i = t & 511;
        unsigned short h, l; split2(W2[i * DM + d], h, l);
        W2hT[d * DI + i] = h; W2lT[d * DI + i] = l;
    }
}

// ---- main fused kernel: 4 waves/block, 32 rows/wave, 8 chunks of 64 inner cols.
__global__ __launch_bounds__(256, 2)
void gml_main(const float* __restrict__ X,
              const float* __restrict__ b1, const float* __restrict__ b2,
              const float* __restrict__ gamma, const float* __restrict__ beta,
              const unsigned short* __restrict__ W1hT, const unsigned short* __restrict__ W1lT,
              const unsigned short* __restrict__ W2hT, const unsigned short* __restrict__ W2lT,
              float* __restrict__ out)
{
    // H chunk per wave: [32 rows][64+8 pad] bf16 hi/lo. Row stride 144B (16-aligned,
    // 2-way max bank aliasing on ds_read_b128 => free).
    __shared__ alignas(16) short sHh[4][32][72];
    __shared__ alignas(16) short sHl[4][32][72];

    const int tid  = threadIdx.x;
    const int wid  = tid >> 6;
    const int lane = tid & 63;
    const int l15  = lane & 15;
    const int lq   = lane >> 4;                   // 0..3
    const int rowbase = blockIdx.x * 128 + wid * 32;

    f32x4 acc2[2][16];                            // [row-tile][out col-tile] = 128 VGPR
    #pragma unroll
    for (int rt = 0; rt < 2; ++rt)
        #pragma unroll
        for (int ot = 0; ot < 16; ++ot)
            acc2[rt][ot] = (f32x4){0.f, 0.f, 0.f, 0.f};

    #pragma unroll 1
    for (int c = 0; c < 8; ++c) {
        const int colbase = c * 64;

        // ---------- layer 1: acc1[32 rows][64 cols] = X @ W1[:, colbase:+64]
        f32x4 acc1[2][4];
        #pragma unroll
        for (int rt = 0; rt < 2; ++rt)
            #pragma unroll
            for (int ct = 0; ct < 4; ++ct)
                acc1[rt][ct] = (f32x4){0.f, 0.f, 0.f, 0.f};

        #pragma unroll
        for (int kt = 0; kt < 8; ++kt) {
            short8 ah[2], al[2];
            #pragma unroll
            for (int rt = 0; rt < 2; ++rt) {
                // A frag: row = lane&15, k = (lane>>4)*8 + j  (8 consecutive k)
                const float* xp = X + (size_t)(rowbase + rt * 16 + l15) * DM + kt * 32 + lq * 8;
                f32x4 xa = *(const f32x4*)xp;
                f32x4 xb = *(const f32x4*)(xp + 4);
                #pragma unroll
                for (int j = 0; j < 8; ++j) {
                    float v = (j < 4) ? xa[j] : xb[j - 4];
                    unsigned short h, l; split2(v, h, l);
                    ah[rt][j] = (short)h; al[rt][j] = (short)l;
                }
            }
            #pragma unroll
            for (int ct = 0; ct < 4; ++ct) {
                const int col = colbase + ct * 16 + l15;   // W1T col index (d_inner)
                const size_t wo = (size_t)col * DM + kt * 32 + lq * 8;
                const short8 bh = *(const short8*)(W1hT + wo);
                const short8 bl = *(const short8*)(W1lT + wo);
                #pragma unroll
                for (int rt = 0; rt < 2; ++rt) {
                    acc1[rt][ct] = MFMA(ah[rt], bh, acc1[rt][ct]);
                    acc1[rt][ct] = MFMA(ah[rt], bl, acc1[rt][ct]);
                    acc1[rt][ct] = MFMA(al[rt], bh, acc1[rt][ct]);
                }
            }
        }

        // bias + SiLU + hi/lo split -> LDS (D layout: row=(lane>>4)*4+r, col=lane&15)
        #pragma unroll
        for (int rt = 0; rt < 2; ++rt)
            #pragma unroll
            for (int ct = 0; ct < 4; ++ct) {
                const float bias = b1[colbase + ct * 16 + l15];
                #pragma unroll
                for (int r = 0; r < 4; ++r) {
                    float x = acc1[rt][ct][r] + bias;
                    float s = x / (1.f + __expf(-x));
                    unsigned short h, l; split2(s, h, l);
                    const int rl = rt * 16 + lq * 4 + r;
                    const int cl = ct * 16 + l15;
                    sHh[wid][rl][cl] = (short)h;
                    sHl[wid][rl][cl] = (short)l;
                }
            }
        __syncthreads();

        // ---------- layer 2: acc2 += SiLU-chunk @ W2[colbase:+64, :]
        #pragma unroll
        for (int kt2 = 0; kt2 < 2; ++kt2) {
            short8 ah2[2], al2[2];
            #pragma unroll
            for (int rt = 0; rt < 2; ++rt) {   // A frag from LDS: one ds_read_b128 each
                ah2[rt] = *(const short8*)(&sHh[wid][rt * 16 + l15][kt2 * 32 + lq * 8]);
                al2[rt] = *(const short8*)(&sHl[wid][rt * 16 + l15][kt2 * 32 + lq * 8]);
            }
            #pragma unroll
            for (int ot = 0; ot < 16; ++ot) {
                const int col = ot * 16 + l15;                 // output d index
                const size_t wo = (size_t)col * DI + colbase + kt2 * 32 + lq * 8;
                const short8 bh = *(const short8*)(W2hT + wo);
                const short8 bl = *(const short8*)(W2lT + wo);
                #pragma unroll
                for (int rt = 0; rt < 2; ++rt) {
                    acc2[rt][ot] = MFMA(ah2[rt], bh, acc2[rt][ot]);
                    acc2[rt][ot] = MFMA(ah2[rt], bl, acc2[rt][ot]);
                    acc2[rt][ot] = MFMA(al2[rt], bh, acc2[rt][ot]);
                }
            }
        }
        __syncthreads();
    }

    // ---------- epilogue: +b2, LayerNorm across 256 cols, *gamma+beta, +residual
    const float inv = 1.f / 256.f;
    #pragma unroll
    for (int rt = 0; rt < 2; ++rt) {
        #pragma unroll
        for (int r = 0; r < 4; ++r) {
            const int row = rowbase + rt * 16 + lq * 4 + r;
            float vv[16];
            float sum = 0.f, ss = 0.f;
            #pragma unroll
            for (int ot = 0; ot < 16; ++ot) {
                float v = acc2[rt][ot][r] + b2[ot * 16 + l15];
                vv[ot] = v; sum += v; ss += v * v;
            }
            #pragma unroll
            for (int m = 1; m < 16; m <<= 1) {   // row lives in 16 lanes (same lane>>4)
                sum += __shfl_xor(sum, m, 64);
                ss  += __shfl_xor(ss,  m, 64);
            }
            const float mean = sum * inv;
            const float var  = ss * inv - mean * mean;
            const float rstd = rsqrtf(var + 1e-5f);
            const size_t rb = (size_t)row * DM;
            #pragma unroll
            for (int ot = 0; ot < 16; ++ot) {
                const int col = ot * 16 + l15;
                out[rb + col] = (vv[ot] - mean) * rstd * gamma[col] + beta[col] + X[rb + col];
            }
        }
    }
}

// ---- slow-but-correct fp32 fallback (only if ws is unexpectedly tiny)
__global__ __launch_bounds__(256)
void gml_naive(const float* __restrict__ X, const float* __restrict__ W1,
               const float* __restrict__ b1, const float* __restrict__ W2,
               const float* __restrict__ b2, const float* __restrict__ gamma,
               const float* __restrict__ beta, float* __restrict__ out)
{
    __shared__ float sx[DM];
    __shared__ float sh[DI];
    __shared__ float red[8];
    const int row = blockIdx.x, t = threadIdx.x;
    const float* xr = X + (size_t)row * DM;
    sx[t] = xr[t];
    __syncthreads();
    #pragma unroll
    for (int rep = 0; rep < 2; ++rep) {
        int i = t + rep * 256;
        float a = 0.f;
        for (int k = 0; k < DM; ++k) a += sx[k] * W1[k * DI + i];
        a += b1[i];
        sh[i] = a / (1.f + __expf(-a));
    }
    __syncthreads();
    float y = 0.f;
    for (int i = 0; i < DI; ++i) y += sh[i] * W2[i * DM + t];
    y += b2[t];
    float s = y, q = y * y;
    for (int m = 1; m < 64; m <<= 1) { s += __shfl_xor(s, m, 64); q += __shfl_xor(q, m, 64); }
    if ((t & 63) == 0) { red[t >> 6] = s; red[4 + (t >> 6)] = q; }
    __syncthreads();
    const float sum = red[0] + red[1] + red[2] + red[3];
    const float ssq = red[4] + red[5] + red[6] + red[7];
    const float mean = sum / 256.f;
    const float rstd = rsqrtf(ssq / 256.f - mean * mean + 1e-5f);
    out[(size_t)row * DM + t] = (y - mean) * rstd * gamma[t] + beta[t] + xr[t];
}

extern "C" void kernel_launch(void* const* d_in, const int* in_sizes, int n_in,
                              void* d_out, int out_size, void* d_ws, size_t ws_size,
                              hipStream_t stream)
{
    const float* slots = (const float*)d_in[0];
    // d_in[1] = adj, d_in[2] = centroids : mathematically unused (permutation cancels)
    const float* W1    = (const float*)d_in[3];
    const float* b1    = (const float*)d_in[4];
    const float* W2    = (const float*)d_in[5];
    const float* b2    = (const float*)d_in[6];
    const float* gamma = (const float*)d_in[7];
    const float* beta  = (const float*)d_in[8];
    float* out = (float*)d_out;

    const size_t need = (size_t)4 * DM * DI * sizeof(unsigned short);  // 1 MiB
    if (ws_size >= need) {
        unsigned short* p   = (unsigned short*)d_ws;
        unsigned short* W1h = p;
        unsigned short* W1l = p + DM * DI;
        unsigned short* W2h = p + 2 * DM * DI;
        unsigned short* W2l = p + 3 * DM * DI;
        hipLaunchKernelGGL(gml_prep, dim3(512), dim3(256), 0, stream, W1, W2, W1h, W1l, W2h, W2l);
        hipLaunchKernelGGL(gml_main, dim3(MROWS / 128), dim3(256), 0, stream,
                           slots, b1, b2, gamma, beta, W1h, W1l, W2h, W2l, out);
    } else {
        hipLaunchKernelGGL(gml_naive, dim3(MROWS), dim3(256), 0, stream,
                           slots, W1, b1, W2, b2, gamma, beta, out);
    }
}

// Round 2
// 640.081 us; speedup vs baseline: 1.2518x; 1.2518x over previous
//
#include <hip/hip_runtime.h>
#include <hip/hip_bf16.h>

// B=512, K=256, D_MODEL=256, D_INNER=512.
// Identity: Hilbert gather/scatter cancels (per-row model):
// out = slots + LN(SiLU(slots@W1+b1)@W2+b2)*gamma+beta. adj/centroids unused.
//
// R2 design: X register-resident per wave (16 rows/wave, hi/lo bf16 frags, loaded
// once -> kills the 8x X re-fetch that dominated R1's 972MB FETCH_SIZE).
// Weights pre-swizzled fragment-major (1KB contiguous per MFMA B-frag, hi/lo
// adjacent). Wave-private LDS H-bounce -> zero block barriers.

#define MROWS (512*256)
#define DM 256
#define DI 512

typedef __attribute__((ext_vector_type(8))) short  short8;
typedef __attribute__((ext_vector_type(4))) float  f32x4;

static __device__ __forceinline__ unsigned short f2bf(float f) {
    union { float f; unsigned u; } c; c.f = f;
    unsigned r = c.u + 0x7FFFu + ((c.u >> 16) & 1u);   // RNE
    return (unsigned short)(r >> 16);
}
static __device__ __forceinline__ float bf2f(unsigned short h) {
    union { unsigned u; float f; } c; c.u = ((unsigned)h) << 16;
    return c.f;
}
static __device__ __forceinline__ void split2(float x, unsigned short& hi, unsigned short& lo) {
    hi = f2bf(x);
    lo = f2bf(x - bf2f(hi));
}
static __device__ __forceinline__ f32x4 MFMA(short8 a, short8 b, f32x4 c) {
    return __builtin_amdgcn_mfma_f32_16x16x32_bf16(a, b, c, 0, 0, 0);
}

// ---- prep: build fragment-major hi/lo bf16 weight arrays.
// W1F: frag f1=(c*8+kt)*4+ct, 1024 shorts each: [0..511]=hi, [512..1023]=lo,
//      element e=lane*8+j -> W1[k=kt*32+(lane>>4)*8+j][i=c*64+ct*16+(lane&15)]
// W2F: frag f2=(c*2+kt2)*16+ot:
//      element e -> W2[i=c*64+kt2*32+(lane>>4)*8+j][d=ot*16+(lane&15)]
__global__ void gml_prep(const float* __restrict__ W1, const float* __restrict__ W2,
                         unsigned short* __restrict__ W1F, unsigned short* __restrict__ W2F)
{
    int t = blockIdx.x * 256 + threadIdx.x;      // 0 .. 131071
    int f = t >> 9, e = t & 511;
    int lane = e >> 3, j = e & 7;
    int l15 = lane & 15, lq = lane >> 4;
    {   // W1: f = ((c*8+kt)*4+ct)
        int ct = f & 3, kt = (f >> 2) & 7, c = f >> 5;
        int k = kt * 32 + lq * 8 + j;
        int i = c * 64 + ct * 16 + l15;
        unsigned short h, l; split2(W1[k * DI + i], h, l);
        W1F[(size_t)f * 1024 + e]       = h;
        W1F[(size_t)f * 1024 + 512 + e] = l;
    }
    {   // W2: f = ((c*2+kt2)*16+ot)
        int ot = f & 15, kt2 = (f >> 4) & 1, c = f >> 5;
        int i = c * 64 + kt2 * 32 + lq * 8 + j;
        int d = ot * 16 + l15;
        unsigned short h, l; split2(W2[i * DM + d], h, l);
        W2F[(size_t)f * 1024 + e]       = h;
        W2F[(size_t)f * 1024 + 512 + e] = l;
    }
}

// ---- main: 4 waves/block, 16 rows/wave, X in regs, no barriers.
__global__ __launch_bounds__(256, 2)
void gml_main(const float* __restrict__ X,
              const float* __restrict__ b1, const float* __restrict__ b2,
              const float* __restrict__ gamma, const float* __restrict__ beta,
              const unsigned short* __restrict__ W1F, const unsigned short* __restrict__ W2F,
              float* __restrict__ out)
{
    // wave-private H bounce: 16 rows x 64 cols, +8 pad (144B rows => <=2-way, free)
    __shared__ short sHh[4][16][72];
    __shared__ short sHl[4][16][72];

    const int tid  = threadIdx.x;
    const int wid  = tid >> 6;
    const int lane = tid & 63;
    const int l15  = lane & 15;
    const int lq   = lane >> 4;
    const int rowbase = blockIdx.x * 64 + wid * 16;

    // ---- X -> registers, hi/lo split, once.
    short8 xh[8], xl[8];
    #pragma unroll
    for (int kt = 0; kt < 8; ++kt) {
        const float* xp = X + (size_t)(rowbase + l15) * DM + kt * 32 + lq * 8;
        f32x4 xa = *(const f32x4*)xp;
        f32x4 xb = *(const f32x4*)(xp + 4);
        #pragma unroll
        for (int j = 0; j < 8; ++j) {
            float v = (j < 4) ? xa[j] : xb[j - 4];
            unsigned short h, l; split2(v, h, l);
            xh[kt][j] = (short)h; xl[kt][j] = (short)l;
        }
    }

    f32x4 acc2[16];
    #pragma unroll
    for (int ot = 0; ot < 16; ++ot) acc2[ot] = (f32x4){0.f, 0.f, 0.f, 0.f};

    #pragma unroll 1
    for (int c = 0; c < 8; ++c) {
        // ---------- layer 1: acc1[16 rows][64 cols]
        f32x4 acc1[4];
        #pragma unroll
        for (int ct = 0; ct < 4; ++ct) acc1[ct] = (f32x4){0.f, 0.f, 0.f, 0.f};

        #pragma unroll
        for (int kt = 0; kt < 8; ++kt) {
            #pragma unroll
            for (int ct = 0; ct < 4; ++ct) {
                const unsigned short* fp = W1F + (size_t)((c * 8 + kt) * 4 + ct) * 1024 + lane * 8;
                const short8 bh = *(const short8*)fp;
                const short8 bl = *(const short8*)(fp + 512);
                acc1[ct] = MFMA(xh[kt], bh, acc1[ct]);
                acc1[ct] = MFMA(xh[kt], bl, acc1[ct]);
                acc1[ct] = MFMA(xl[kt], bh, acc1[ct]);
            }
        }

        // bias + SiLU + split -> wave-private LDS (no barrier needed)
        #pragma unroll
        for (int ct = 0; ct < 4; ++ct) {
            const float bias = b1[c * 64 + ct * 16 + l15];
            #pragma unroll
            for (int r = 0; r < 4; ++r) {
                float x = acc1[ct][r] + bias;
                float s = x / (1.f + __expf(-x));
                unsigned short h, l; split2(s, h, l);
                sHh[wid][lq * 4 + r][ct * 16 + l15] = (short)h;
                sHl[wid][lq * 4 + r][ct * 16 + l15] = (short)l;
            }
        }

        // ---------- layer 2
        #pragma unroll
        for (int kt2 = 0; kt2 < 2; ++kt2) {
            const short8 ah2 = *(const short8*)(&sHh[wid][l15][kt2 * 32 + lq * 8]);
            const short8 al2 = *(const short8*)(&sHl[wid][l15][kt2 * 32 + lq * 8]);
            #pragma unroll
            for (int ot = 0; ot < 16; ++ot) {
                const unsigned short* fp = W2F + (size_t)((c * 2 + kt2) * 16 + ot) * 1024 + lane * 8;
                const short8 bh = *(const short8*)fp;
                const short8 bl = *(const short8*)(fp + 512);
                acc2[ot] = MFMA(ah2, bh, acc2[ot]);
                acc2[ot] = MFMA(ah2, bl, acc2[ot]);
                acc2[ot] = MFMA(al2, bh, acc2[ot]);
            }
        }
    }

    // ---------- epilogue: +b2, LN over 256 cols, *gamma+beta, +residual
    const float inv = 1.f / 256.f;
    #pragma unroll
    for (int r = 0; r < 4; ++r) {
        const int row = rowbase + lq * 4 + r;
        float vv[16];
        float sum = 0.f, ss = 0.f;
        #pragma unroll
        for (int ot = 0; ot < 16; ++ot) {
            float v = acc2[ot][r] + b2[ot * 16 + l15];
            vv[ot] = v; sum += v; ss += v * v;
        }
        #pragma unroll
        for (int m = 1; m < 16; m <<= 1) {      // row lives in 16 lanes (same lq)
            sum += __shfl_xor(sum, m, 64);
            ss  += __shfl_xor(ss,  m, 64);
        }
        const float mean = sum * inv;
        const float var  = ss * inv - mean * mean;
        const float rstd = rsqrtf(var + 1e-5f);
        const size_t rb = (size_t)row * DM;
        #pragma unroll
        for (int ot = 0; ot < 16; ++ot) {
            const int col = ot * 16 + l15;
            out[rb + col] = (vv[ot] - mean) * rstd * gamma[col] + beta[col] + X[rb + col];
        }
    }
}

// ---- slow-but-correct fp32 fallback (only if ws is unexpectedly tiny)
__global__ __launch_bounds__(256)
void gml_naive(const float* __restrict__ X, const float* __restrict__ W1,
               const float* __restrict__ b1, const float* __restrict__ W2,
               const float* __restrict__ b2, const float* __restrict__ gamma,
               const float* __restrict__ beta, float* __restrict__ out)
{
    __shared__ float sx[DM];
    __shared__ float sh[DI];
    __shared__ float red[8];
    const int row = blockIdx.x, t = threadIdx.x;
    const float* xr = X + (size_t)row * DM;
    sx[t] = xr[t];
    __syncthreads();
    #pragma unroll
    for (int rep = 0; rep < 2; ++rep) {
        int i = t + rep * 256;
        float a = 0.f;
        for (int k = 0; k < DM; ++k) a += sx[k] * W1[k * DI + i];
        a += b1[i];
        sh[i] = a / (1.f + __expf(-a));
    }
    __syncthreads();
    float y = 0.f;
    for (int i = 0; i < DI; ++i) y += sh[i] * W2[i * DM + t];
    y += b2[t];
    float s = y, q = y * y;
    for (int m = 1; m < 64; m <<= 1) { s += __shfl_xor(s, m, 64); q += __shfl_xor(q, m, 64); }
    if ((t & 63) == 0) { red[t >> 6] = s; red[4 + (t >> 6)] = q; }
    __syncthreads();
    const float sum = red[0] + red[1] + red[2] + red[3];
    const float ssq = red[4] + red[5] + red[6] + red[7];
    const float mean = sum / 256.f;
    const float rstd = rsqrtf(ssq / 256.f - mean * mean + 1e-5f);
    out[(size_t)row * DM + t] = (y - mean) * rstd * gamma[t] + beta[t] + xr[t];
}

extern "C" void kernel_launch(void* const* d_in, const int* in_sizes, int n_in,
                              void* d_out, int out_size, void* d_ws, size_t ws_size,
                              hipStream_t stream)
{
    const float* slots = (const float*)d_in[0];
    // d_in[1]=adj, d_in[2]=centroids : unused (permutation cancels)
    const float* W1    = (const float*)d_in[3];
    const float* b1    = (const float*)d_in[4];
    const float* W2    = (const float*)d_in[5];
    const float* b2    = (const float*)d_in[6];
    const float* gamma = (const float*)d_in[7];
    const float* beta  = (const float*)d_in[8];
    float* out = (float*)d_out;

    const size_t need = (size_t)2 * 256 * 1024 * sizeof(unsigned short);  // 1 MiB
    if (ws_size >= need) {
        unsigned short* W1F = (unsigned short*)d_ws;
        unsigned short* W2F = W1F + (size_t)256 * 1024;
        hipLaunchKernelGGL(gml_prep, dim3(512), dim3(256), 0, stream, W1, W2, W1F, W2F);
        hipLaunchKernelGGL(gml_main, dim3(MROWS / 64), dim3(256), 0, stream,
                           slots, b1, b2, gamma, beta, W1F, W2F, out);
    } else {
        hipLaunchKernelGGL(gml_naive, dim3(MROWS), dim3(256), 0, stream,
                           slots, W1, b1, W2, b2, gamma, beta, out);
    }
}

// Round 3
// 338.486 us; speedup vs baseline: 2.3671x; 1.8910x over previous
//
#include <hip/hip_runtime.h>
#include <hip/hip_bf16.h>

// B=512, K=256, D_MODEL=256, D_INNER=512.
// Identity: Hilbert gather/scatter cancels (per-row model):
// out = slots + LN(SiLU(slots@W1+b1)@W2+b2)*gamma+beta. adj/centroids unused.
//
// R3: 32 rows per block (4 waves share rows, col-split 4-way on both layers).
// Per-wave weight traffic halves vs R2 (4.3 GB total). X-hi register-resident,
// X-lo in swizzled LDS. Explicit double-buffered weight-register staging keeps
// 4-8 loads in flight. H exchanged via swizzled LDS, 2 barriers/chunk.

#define MROWS (512*256)
#define DM 256
#define DI 512

typedef __attribute__((ext_vector_type(8))) short  short8;
typedef __attribute__((ext_vector_type(4))) float  f32x4;

static __device__ __forceinline__ unsigned short f2bf(float f) {
    union { float f; unsigned u; } c; c.f = f;
    unsigned r = c.u + 0x7FFFu + ((c.u >> 16) & 1u);   // RNE
    return (unsigned short)(r >> 16);
}
static __device__ __forceinline__ float bf2f(unsigned short h) {
    union { unsigned u; float f; } c; c.u = ((unsigned)h) << 16;
    return c.f;
}
static __device__ __forceinline__ void split2(float x, unsigned short& hi, unsigned short& lo) {
    hi = f2bf(x);
    lo = f2bf(x - bf2f(hi));
}
static __device__ __forceinline__ f32x4 MFMA(short8 a, short8 b, f32x4 c) {
    return __builtin_amdgcn_mfma_f32_16x16x32_bf16(a, b, c, 0, 0, 0);
}

// ---- prep: fragment-major hi/lo weights.
// W1F frag f = tile16*8+kt (tile16 0..31, kt 0..7), 1024 shorts (512 hi | 512 lo)
//   elem e=lane*8+j  ->  W1[k=kt*32+(lane>>4)*8+j][i=tile16*16+(lane&15)]
// W2F frag f = dtile*16+ks (dtile 0..15, ks 0..15)
//   elem e           ->  W2[i=ks*32+(lane>>4)*8+j][d=dtile*16+(lane&15)]
__global__ void gml_prep(const float* __restrict__ W1, const float* __restrict__ W2,
                         unsigned short* __restrict__ W1F, unsigned short* __restrict__ W2F)
{
    int t = blockIdx.x * 256 + threadIdx.x;      // 0 .. 131071
    int f = t >> 9, e = t & 511;
    int lane = e >> 3, j = e & 7;
    int l15 = lane & 15, lq = lane >> 4;
    {
        int tile16 = f >> 3, kt = f & 7;
        int i = tile16 * 16 + l15;
        int k = kt * 32 + lq * 8 + j;
        unsigned short h, l; split2(W1[k * DI + i], h, l);
        W1F[(size_t)f * 1024 + e]       = h;
        W1F[(size_t)f * 1024 + 512 + e] = l;
    }
    {
        int dtile = f >> 4, ks = f & 15;
        int d = dtile * 16 + l15;
        int i = ks * 32 + lq * 8 + j;
        unsigned short h, l; split2(W2[i * DM + d], h, l);
        W2F[(size_t)f * 1024 + e]       = h;
        W2F[(size_t)f * 1024 + 512 + e] = l;
    }
}

__global__ __launch_bounds__(256, 2)
void gml_main(const float* __restrict__ X,
              const float* __restrict__ b1, const float* __restrict__ b2,
              const float* __restrict__ gamma, const float* __restrict__ beta,
              const unsigned short* __restrict__ W1F, const unsigned short* __restrict__ W2F,
              float* __restrict__ out)
{
    // X-lo: [32 rows][256 k] bf16, row stride 512B, swizzle ^((row&31)<<4)
    __shared__ short sXl[32 * 256];
    // H hi/lo: [32 rows][64 k + pad to 128] bf16, row stride 256B, swizzle ^((row&15)<<4)
    __shared__ short sHh[32 * 128];
    __shared__ short sHl[32 * 128];
    __shared__ float pS[4][32], pQ[4][32];

    const int tid  = threadIdx.x;
    const int wid  = tid >> 6;
    const int lane = tid & 63;
    const int l15  = lane & 15;
    const int lq   = lane >> 4;
    const int rowbase = blockIdx.x * 32;

    // ---- X load + split: hi resident in regs, lo -> LDS (kt partitioned by wave)
    short8 xh[2][8];
    #pragma unroll
    for (int rt = 0; rt < 2; ++rt) {
        #pragma unroll
        for (int kt = 0; kt < 8; ++kt) {
            const int row = rt * 16 + l15;
            const float* xp = X + (size_t)(rowbase + row) * DM + kt * 32 + lq * 8;
            f32x4 xa = *(const f32x4*)xp;
            f32x4 xb = *(const f32x4*)(xp + 4);
            short8 lo8;
            #pragma unroll
            for (int j = 0; j < 8; ++j) {
                float v = (j < 4) ? xa[j] : xb[j - 4];
                unsigned short h, l; split2(v, h, l);
                xh[rt][kt][j] = (short)h; lo8[j] = (short)l;
            }
            if ((kt >> 1) == wid) {
                int byt = (row * 512 + (kt * 32 + lq * 8) * 2) ^ ((row & 31) << 4);
                *(short8*)(sXl + (byt >> 1)) = lo8;
            }
        }
    }

    f32x4 acc2[2][4];
    #pragma unroll
    for (int rt = 0; rt < 2; ++rt)
        #pragma unroll
        for (int ot = 0; ot < 4; ++ot)
            acc2[rt][ot] = (f32x4){0.f, 0.f, 0.f, 0.f};

    __syncthreads();

    #pragma unroll 1
    for (int c = 0; c < 8; ++c) {
        // ---------- layer 1: wave computes H[0..31][c*64 + wid*16 .. +16]
        f32x4 acc1[2] = {(f32x4){0.f,0.f,0.f,0.f}, (f32x4){0.f,0.f,0.f,0.f}};
        const unsigned short* w1p = W1F + (size_t)((c * 4 + wid) * 8) * 1024 + lane * 8;

        short8 wb[2][2][2];                      // [buf][kt-in-batch][hi/lo]
        #pragma unroll
        for (int t = 0; t < 2; ++t) {            // preload kt 0,1
            wb[0][t][0] = *(const short8*)(w1p + t * 1024);
            wb[0][t][1] = *(const short8*)(w1p + t * 1024 + 512);
        }
        #pragma unroll
        for (int kb = 0; kb < 4; ++kb) {
            const int p = kb & 1;
            if (kb < 3) {
                #pragma unroll
                for (int t = 0; t < 2; ++t) {
                    wb[1 - p][t][0] = *(const short8*)(w1p + (kb * 2 + 2 + t) * 1024);
                    wb[1 - p][t][1] = *(const short8*)(w1p + (kb * 2 + 2 + t) * 1024 + 512);
                }
            }
            #pragma unroll
            for (int t = 0; t < 2; ++t) {
                const int kt = kb * 2 + t;
                short8 xlt[2];
                #pragma unroll
                for (int rt = 0; rt < 2; ++rt) {
                    const int row = rt * 16 + l15;
                    int byt = (row * 512 + (kt * 32 + lq * 8) * 2) ^ ((row & 31) << 4);
                    xlt[rt] = *(const short8*)(sXl + (byt >> 1));
                }
                #pragma unroll
                for (int rt = 0; rt < 2; ++rt) {
                    acc1[rt] = MFMA(xh[rt][kt], wb[p][t][0], acc1[rt]);
                    acc1[rt] = MFMA(xh[rt][kt], wb[p][t][1], acc1[rt]);
                    acc1[rt] = MFMA(xlt[rt],    wb[p][t][0], acc1[rt]);
                }
            }
        }

        // ---------- bias + SiLU + split -> H LDS
        const float bias = b1[c * 64 + wid * 16 + l15];
        #pragma unroll
        for (int rt = 0; rt < 2; ++rt) {
            #pragma unroll
            for (int r = 0; r < 4; ++r) {
                const int row = rt * 16 + lq * 4 + r;
                float x = acc1[rt][r] + bias;
                float s = x / (1.f + __expf(-x));
                unsigned short h, l; split2(s, h, l);
                int byt = (row * 256 + (wid * 16 + l15) * 2) ^ ((row & 15) << 4);
                sHh[byt >> 1] = (short)h;
                sHl[byt >> 1] = (short)l;
            }
        }

        // preload first W2 batch (independent of LDS) before the barrier
        const unsigned short* w2p = W2F + (size_t)((wid * 4) * 16 + c * 2) * 1024 + lane * 8;
        short8 vb[2][2][2];                      // [buf][ot-in-pair][hi/lo]
        #pragma unroll
        for (int t = 0; t < 2; ++t) {            // u=0: kt2=0, ots {0,1}
            vb[0][t][0] = *(const short8*)(w2p + (size_t)t * 16 * 1024);
            vb[0][t][1] = *(const short8*)(w2p + (size_t)t * 16 * 1024 + 512);
        }
        __syncthreads();

        // ---------- layer 2: acc2 += H @ W2[c*64..+64][wave's 64 cols]
        #pragma unroll
        for (int kt2 = 0; kt2 < 2; ++kt2) {
            short8 a2h[2], a2l[2];
            #pragma unroll
            for (int rt = 0; rt < 2; ++rt) {
                const int row = rt * 16 + l15;
                int byt = (row * 256 + (kt2 * 32 + lq * 8) * 2) ^ ((row & 15) << 4);
                a2h[rt] = *(const short8*)(sHh + (byt >> 1));
                a2l[rt] = *(const short8*)(sHl + (byt >> 1));
            }
            #pragma unroll
            for (int op = 0; op < 2; ++op) {
                const int u = kt2 * 2 + op;
                const int p = u & 1;
                if (u < 3) {
                    const int un = u + 1;
                    const int nkt2 = un >> 1, nop = un & 1;
                    #pragma unroll
                    for (int t = 0; t < 2; ++t) {
                        const size_t off = (size_t)((nop * 2 + t) * 16 + nkt2) * 1024;
                        vb[1 - p][t][0] = *(const short8*)(w2p + off);
                        vb[1 - p][t][1] = *(const short8*)(w2p + off + 512);
                    }
                }
                #pragma unroll
                for (int t = 0; t < 2; ++t) {
                    const int ot = op * 2 + t;
                    #pragma unroll
                    for (int rt = 0; rt < 2; ++rt) {
                        acc2[rt][ot] = MFMA(a2h[rt], vb[p][t][0], acc2[rt][ot]);
                        acc2[rt][ot] = MFMA(a2h[rt], vb[p][t][1], acc2[rt][ot]);
                        acc2[rt][ot] = MFMA(a2l[rt], vb[p][t][0], acc2[rt][ot]);
                    }
                }
            }
        }
        __syncthreads();
    }

    // ---------- epilogue: +b2, block-wide LN over 256 cols, *gamma+beta, +residual
    float b2v[4];
    #pragma unroll
    for (int ot = 0; ot < 4; ++ot) b2v[ot] = b2[(wid * 4 + ot) * 16 + l15];

    #pragma unroll
    for (int rt = 0; rt < 2; ++rt) {
        #pragma unroll
        for (int r = 0; r < 4; ++r) {
            float s = 0.f, q = 0.f;
            #pragma unroll
            for (int ot = 0; ot < 4; ++ot) {
                float v = acc2[rt][ot][r] + b2v[ot];
                acc2[rt][ot][r] = v;
                s += v; q += v * v;
            }
            #pragma unroll
            for (int m = 1; m < 16; m <<= 1) {
                s += __shfl_xor(s, m, 64);
                q += __shfl_xor(q, m, 64);
            }
            if (l15 == 0) {
                const int row = rt * 16 + lq * 4 + r;
                pS[wid][row] = s; pQ[wid][row] = q;
            }
        }
    }
    __syncthreads();

    const float inv = 1.f / 256.f;
    #pragma unroll
    for (int rt = 0; rt < 2; ++rt) {
        #pragma unroll
        for (int r = 0; r < 4; ++r) {
            const int rl = rt * 16 + lq * 4 + r;
            const float s = pS[0][rl] + pS[1][rl] + pS[2][rl] + pS[3][rl];
            const float q = pQ[0][rl] + pQ[1][rl] + pQ[2][rl] + pQ[3][rl];
            const float mean = s * inv;
            const float rstd = rsqrtf(q * inv - mean * mean + 1e-5f);
            const size_t rb = (size_t)(rowbase + rl) * DM;
            #pragma unroll
            for (int ot = 0; ot < 4; ++ot) {
                const int col = (wid * 4 + ot) * 16 + l15;
                out[rb + col] = (acc2[rt][ot][r] - mean) * rstd * gamma[col] + beta[col] + X[rb + col];
            }
        }
    }
}

// ---- slow-but-correct fp32 fallback (only if ws is unexpectedly tiny)
__global__ __launch_bounds__(256)
void gml_naive(const float* __restrict__ X, const float* __restrict__ W1,
               const float* __restrict__ b1, const float* __restrict__ W2,
               const float* __restrict__ b2, const float* __restrict__ gamma,
               const float* __restrict__ beta, float* __restrict__ out)
{
    __shared__ float sx[DM];
    __shared__ float sh[DI];
    __shared__ float red[8];
    const int row = blockIdx.x, t = threadIdx.x;
    const float* xr = X + (size_t)row * DM;
    sx[t] = xr[t];
    __syncthreads();
    #pragma unroll
    for (int rep = 0; rep < 2; ++rep) {
        int i = t + rep * 256;
        float a = 0.f;
        for (int k = 0; k < DM; ++k) a += sx[k] * W1[k * DI + i];
        a += b1[i];
        sh[i] = a / (1.f + __expf(-a));
    }
    __syncthreads();
    float y = 0.f;
    for (int i = 0; i < DI; ++i) y += sh[i] * W2[i * DM + t];
    y += b2[t];
    float s = y, q = y * y;
    for (int m = 1; m < 64; m <<= 1) { s += __shfl_xor(s, m, 64); q += __shfl_xor(q, m, 64); }
    if ((t & 63) == 0) { red[t >> 6] = s; red[4 + (t >> 6)] = q; }
    __syncthreads();
    const float sum = red[0] + red[1] + red[2] + red[3];
    const float ssq = red[4] + red[5] + red[6] + red[7];
    const float mean = sum / 256.f;
    const float rstd = rsqrtf(ssq / 256.f - mean * mean + 1e-5f);
    out[(size_t)row * DM + t] = (y - mean) * rstd * gamma[t] + beta[t] + xr[t];
}

extern "C" void kernel_launch(void* const* d_in, const int* in_sizes, int n_in,
                              void* d_out, int out_size, void* d_ws, size_t ws_size,
                              hipStream_t stream)
{
    const float* slots = (const float*)d_in[0];
    // d_in[1]=adj, d_in[2]=centroids : unused (permutation cancels)
    const float* W1    = (const float*)d_in[3];
    const float* b1    = (const float*)d_in[4];
    const float* W2    = (const float*)d_in[5];
    const float* b2    = (const float*)d_in[6];
    const float* gamma = (const float*)d_in[7];
    const float* beta  = (const float*)d_in[8];
    float* out = (float*)d_out;

    const size_t need = (size_t)2 * 256 * 1024 * sizeof(unsigned short);  // 1 MiB
    if (ws_size >= need) {
        unsigned short* W1F = (unsigned short*)d_ws;
        unsigned short* W2F = W1F + (size_t)256 * 1024;
        hipLaunchKernelGGL(gml_prep, dim3(512), dim3(256), 0, stream, W1, W2, W1F, W2F);
        hipLaunchKernelGGL(gml_main, dim3(MROWS / 32), dim3(256), 0, stream,
                           slots, b1, b2, gamma, beta, W1F, W2F, out);
    } else {
        hipLaunchKernelGGL(gml_naive, dim3(MROWS), dim3(256), 0, stream,
                           slots, W1, b1, W2, b2, gamma, beta, out);
    }
}

// Round 6
// 239.708 us; speedup vs baseline: 3.3425x; 1.4121x over previous
//
#include <hip/hip_runtime.h>
#include <hip/hip_bf16.h>

// B=512, K=256, D_MODEL=256, D_INNER=512.
// Identity: Hilbert gather/scatter cancels (per-row model):
// out = slots + LN(SiLU(slots@W1+b1)@W2+b2)*gamma+beta. adj/centroids unused.
//
// R4 (2nd resubmit; two UnresponsiveContainer infra failures, error occurs at
// connection setup before any kernel runs): 64-row blocks (8 waves, 512 thr).
// Full weight set streamed ONCE per block (2.1 GB total, half of R3). X hi/lo
// LDS-resident (swizzled) -> per-wave VGPR ~120 -> launch_bounds(512,4) ->
// 4 waves/SIMD (2x R3's latency hiding). Wave split: row-half (w>>2) x
// col-strip (w&3). LDS 80KB -> 2 blocks/CU.

#define MROWS (512*256)
#define DM 256
#define DI 512

typedef __attribute__((ext_vector_type(8))) short  short8;
typedef __attribute__((ext_vector_type(4))) float  f32x4;

static __device__ __forceinline__ unsigned short f2bf(float f) {
    union { float f; unsigned u; } c; c.f = f;
    unsigned r = c.u + 0x7FFFu + ((c.u >> 16) & 1u);   // RNE
    return (unsigned short)(r >> 16);
}
static __device__ __forceinline__ float bf2f(unsigned short h) {
    union { unsigned u; float f; } c; c.u = ((unsigned)h) << 16;
    return c.f;
}
static __device__ __forceinline__ void split2(float x, unsigned short& hi, unsigned short& lo) {
    hi = f2bf(x);
    lo = f2bf(x - bf2f(hi));
}
static __device__ __forceinline__ f32x4 MFMA(short8 a, short8 b, f32x4 c) {
    return __builtin_amdgcn_mfma_f32_16x16x32_bf16(a, b, c, 0, 0, 0);
}

// ---- prep: fragment-major hi/lo weights.
// W1F frag f = tile16*8+kt (tile16 0..31, kt 0..7), 1024 shorts (512 hi | 512 lo)
//   elem e=lane*8+j  ->  W1[k=kt*32+(lane>>4)*8+j][i=tile16*16+(lane&15)]
// W2F frag f = dtile*16+ks (dtile 0..15, ks 0..15)
//   elem e           ->  W2[i=ks*32+(lane>>4)*8+j][d=dtile*16+(lane&15)]
__global__ void gml_prep(const float* __restrict__ W1, const float* __restrict__ W2,
                         unsigned short* __restrict__ W1F, unsigned short* __restrict__ W2F)
{
    int t = blockIdx.x * 256 + threadIdx.x;      // 0 .. 131071
    int f = t >> 9, e = t & 511;
    int lane = e >> 3, j = e & 7;
    int l15 = lane & 15, lq = lane >> 4;
    {
        int tile16 = f >> 3, kt = f & 7;
        int i = tile16 * 16 + l15;
        int k = kt * 32 + lq * 8 + j;
        unsigned short h, l; split2(W1[k * DI + i], h, l);
        W1F[(size_t)f * 1024 + e]       = h;
        W1F[(size_t)f * 1024 + 512 + e] = l;
    }
    {
        int dtile = f >> 4, ks = f & 15;
        int d = dtile * 16 + l15;
        int i = ks * 32 + lq * 8 + j;
        unsigned short h, l; split2(W2[i * DM + d], h, l);
        W2F[(size_t)f * 1024 + e]       = h;
        W2F[(size_t)f * 1024 + 512 + e] = l;
    }
}

__global__ __launch_bounds__(512, 4)
void gml_main(const float* __restrict__ X,
              const float* __restrict__ b1, const float* __restrict__ b2,
              const float* __restrict__ gamma, const float* __restrict__ beta,
              const unsigned short* __restrict__ W1F, const unsigned short* __restrict__ W2F,
              float* __restrict__ out)
{
    // X hi/lo: [64 rows][256 k] bf16, row stride 512B, byte-swizzle ^((row&7)<<4)
    __shared__ short sXh[64 * 256];   // 32 KB
    __shared__ short sXl[64 * 256];   // 32 KB
    // H chunk hi/lo: [64 rows][64 k] bf16, row stride 128B, same swizzle
    __shared__ short sHh[64 * 64];    // 8 KB
    __shared__ short sHl[64 * 64];    // 8 KB   -> total exactly 80 KB
    // LN partials aliased into sXl (dead after the chunk loop)
    float* pS = (float*)sXl;          // [4 strips][64 rows]
    float* pQ = pS + 256;

    const int tid  = threadIdx.x;
    const int w    = tid >> 6;        // wave 0..7
    const int lane = tid & 63;
    const int l15  = lane & 15;
    const int lq   = lane >> 4;
    const int half = w >> 2;          // row half owned for compute
    const int cs   = w & 3;           // column strip
    const int rowbase = blockIdx.x * 64;

    // ---- X -> LDS hi/lo. Wave w loads k-slice [w*32, w*32+32) for all 64 rows.
    #pragma unroll
    for (int rt = 0; rt < 4; ++rt) {
        const int row = rt * 16 + l15;
        const float* xp = X + (size_t)(rowbase + row) * DM + w * 32 + lq * 8;
        f32x4 xa = *(const f32x4*)xp;
        f32x4 xb = *(const f32x4*)(xp + 4);
        short8 h8, l8;
        #pragma unroll
        for (int j = 0; j < 8; ++j) {
            float v = (j < 4) ? xa[j] : xb[j - 4];
            unsigned short h, l; split2(v, h, l);
            h8[j] = (short)h; l8[j] = (short)l;
        }
        const int byt = (row * 512 + (w * 32 + lq * 8) * 2) ^ ((row & 7) << 4);
        *(short8*)((char*)sXh + byt) = h8;
        *(short8*)((char*)sXl + byt) = l8;
    }

    f32x4 acc2[2][4];
    #pragma unroll
    for (int rt = 0; rt < 2; ++rt)
        #pragma unroll
        for (int ot = 0; ot < 4; ++ot)
            acc2[rt][ot] = (f32x4){0.f, 0.f, 0.f, 0.f};

    __syncthreads();

    #pragma unroll 1
    for (int c = 0; c < 8; ++c) {
        // ---------- layer 1: wave computes H[half*32..+32][c*64 + cs*16 .. +16]
        f32x4 acc1[2] = {(f32x4){0.f,0.f,0.f,0.f}, (f32x4){0.f,0.f,0.f,0.f}};
        const unsigned short* w1p = W1F + (size_t)((c * 4 + cs) * 8) * 1024 + lane * 8;

        short8 wb[2][2];                              // depth-1 double buffer [buf][hi/lo]
        wb[0][0] = *(const short8*)(w1p);
        wb[0][1] = *(const short8*)(w1p + 512);
        #pragma unroll
        for (int kt = 0; kt < 8; ++kt) {
            const int p = kt & 1;
            if (kt < 7) {
                wb[1 - p][0] = *(const short8*)(w1p + (kt + 1) * 1024);
                wb[1 - p][1] = *(const short8*)(w1p + (kt + 1) * 1024 + 512);
            }
            short8 ah[2], al[2];
            #pragma unroll
            for (int rt = 0; rt < 2; ++rt) {
                const int row = half * 32 + rt * 16 + l15;
                const int byt = (row * 512 + (kt * 32 + lq * 8) * 2) ^ ((row & 7) << 4);
                ah[rt] = *(const short8*)((char*)sXh + byt);
                al[rt] = *(const short8*)((char*)sXl + byt);
            }
            #pragma unroll
            for (int rt = 0; rt < 2; ++rt) {
                acc1[rt] = MFMA(ah[rt], wb[p][0], acc1[rt]);
                acc1[rt] = MFMA(ah[rt], wb[p][1], acc1[rt]);
                acc1[rt] = MFMA(al[rt], wb[p][0], acc1[rt]);
            }
        }

        // ---------- bias + SiLU + split -> H LDS
        const float bias = b1[c * 64 + cs * 16 + l15];
        #pragma unroll
        for (int rt = 0; rt < 2; ++rt) {
            #pragma unroll
            for (int r = 0; r < 4; ++r) {
                const int row = half * 32 + rt * 16 + lq * 4 + r;
                float x = acc1[rt][r] + bias;
                float s = x / (1.f + __expf(-x));
                unsigned short h, l; split2(s, h, l);
                const int byt = (row * 128 + (cs * 16 + l15) * 2) ^ ((row & 7) << 4);
                *(short*)((char*)sHh + byt) = (short)h;
                *(short*)((char*)sHl + byt) = (short)l;
            }
        }

        // prefetch first W2 frag (global, independent of LDS) before the barrier
        const unsigned short* w2p = W2F + ((size_t)(cs * 4) * 16 + c * 2) * 1024 + lane * 8;
        short8 vb[2][2];
        vb[0][0] = *(const short8*)(w2p);
        vb[0][1] = *(const short8*)(w2p + 512);
        __syncthreads();

        // ---------- layer 2: acc2 += H @ W2[c*64..+64][cs*64 .. +64]
        #pragma unroll
        for (int kt2 = 0; kt2 < 2; ++kt2) {
            short8 a2h[2], a2l[2];
            #pragma unroll
            for (int rt = 0; rt < 2; ++rt) {
                const int row = half * 32 + rt * 16 + l15;
                const int byt = (row * 128 + (kt2 * 32 + lq * 8) * 2) ^ ((row & 7) << 4);
                a2h[rt] = *(const short8*)((char*)sHh + byt);
                a2l[rt] = *(const short8*)((char*)sHl + byt);
            }
            #pragma unroll
            for (int ot = 0; ot < 4; ++ot) {
                const int u = kt2 * 4 + ot;
                const int p = u & 1;
                if (u < 7) {
                    const int un = u + 1;
                    const size_t off = (size_t)((un & 3) * 16 + (un >> 2)) * 1024;
                    vb[1 - p][0] = *(const short8*)(w2p + off);
                    vb[1 - p][1] = *(const short8*)(w2p + off + 512);
                }
                #pragma unroll
                for (int rt = 0; rt < 2; ++rt) {
                    acc2[rt][ot] = MFMA(a2h[rt], vb[p][0], acc2[rt][ot]);
                    acc2[rt][ot] = MFMA(a2h[rt], vb[p][1], acc2[rt][ot]);
                    acc2[rt][ot] = MFMA(a2l[rt], vb[p][0], acc2[rt][ot]);
                }
            }
        }
        __syncthreads();
    }

    // ---------- epilogue: +b2, block-wide LN over 256 cols, *gamma+beta, +residual
    float b2v[4];
    #pragma unroll
    for (int ot = 0; ot < 4; ++ot) b2v[ot] = b2[cs * 64 + ot * 16 + l15];

    #pragma unroll
    for (int rt = 0; rt < 2; ++rt) {
        #pragma unroll
        for (int r = 0; r < 4; ++r) {
            float s = 0.f, q = 0.f;
            #pragma unroll
            for (int ot = 0; ot < 4; ++ot) {
                float v = acc2[rt][ot][r] + b2v[ot];
                acc2[rt][ot][r] = v;
                s += v; q += v * v;
            }
            #pragma unroll
            for (int m = 1; m < 16; m <<= 1) {
                s += __shfl_xor(s, m, 64);
                q += __shfl_xor(q, m, 64);
            }
            if (l15 == 0) {
                const int rowl = half * 32 + rt * 16 + lq * 4 + r;
                pS[cs * 64 + rowl] = s;
                pQ[cs * 64 + rowl] = q;
            }
        }
    }
    __syncthreads();

    const float inv = 1.f / 256.f;
    #pragma unroll
    for (int rt = 0; rt < 2; ++rt) {
        #pragma unroll
        for (int r = 0; r < 4; ++r) {
            const int rowl = half * 32 + rt * 16 + lq * 4 + r;
            const float s = pS[rowl] + pS[64 + rowl] + pS[128 + rowl] + pS[192 + rowl];
            const float q = pQ[rowl] + pQ[64 + rowl] + pQ[128 + rowl] + pQ[192 + rowl];
            const float mean = s * inv;
            const float rstd = rsqrtf(q * inv - mean * mean + 1e-5f);
            const size_t rb = (size_t)(rowbase + rowl) * DM;
            #pragma unroll
            for (int ot = 0; ot < 4; ++ot) {
                const int col = cs * 64 + ot * 16 + l15;
                out[rb + col] = (acc2[rt][ot][r] - mean) * rstd * gamma[col] + beta[col] + X[rb + col];
            }
        }
    }
}

// ---- slow-but-correct fp32 fallback (only if ws is unexpectedly tiny)
__global__ __launch_bounds__(256)
void gml_naive(const float* __restrict__ X, const float* __restrict__ W1,
               const float* __restrict__ b1, const float* __restrict__ W2,
               const float* __restrict__ b2, const float* __restrict__ gamma,
               const float* __restrict__ beta, float* __restrict__ out)
{
    __shared__ float sx[DM];
    __shared__ float sh[DI];
    __shared__ float red[8];
    const int row = blockIdx.x, t = threadIdx.x;
    const float* xr = X + (size_t)row * DM;
    sx[t] = xr[t];
    __syncthreads();
    #pragma unroll
    for (int rep = 0; rep < 2; ++rep) {
        int i = t + rep * 256;
        float a = 0.f;
        for (int k = 0; k < DM; ++k) a += sx[k] * W1[k * DI + i];
        a += b1[i];
        sh[i] = a / (1.f + __expf(-a));
    }
    __syncthreads();
    float y = 0.f;
    for (int i = 0; i < DI; ++i) y += sh[i] * W2[i * DM + t];
    y += b2[t];
    float s = y, q = y * y;
    for (int m = 1; m < 64; m <<= 1) { s += __shfl_xor(s, m, 64); q += __shfl_xor(q, m, 64); }
    if ((t & 63) == 0) { red[t >> 6] = s; red[4 + (t >> 6)] = q; }
    __syncthreads();
    const float sum = red[0] + red[1] + red[2] + red[3];
    const float ssq = red[4] + red[5] + red[6] + red[7];
    const float mean = sum / 256.f;
    const float rstd = rsqrtf(ssq / 256.f - mean * mean + 1e-5f);
    out[(size_t)row * DM + t] = (y - mean) * rstd * gamma[t] + beta[t] + xr[t];
}

extern "C" void kernel_launch(void* const* d_in, const int* in_sizes, int n_in,
                              void* d_out, int out_size, void* d_ws, size_t ws_size,
                              hipStream_t stream)
{
    const float* slots = (const float*)d_in[0];
    // d_in[1]=adj, d_in[2]=centroids : unused (permutation cancels)
    const float* W1    = (const float*)d_in[3];
    const float* b1    = (const float*)d_in[4];
    const float* W2    = (const float*)d_in[5];
    const float* b2    = (const float*)d_in[6];
    const float* gamma = (const float*)d_in[7];
    const float* beta  = (const float*)d_in[8];
    float* out = (float*)d_out;

    const size_t need = (size_t)2 * 256 * 1024 * sizeof(unsigned short);  // 1 MiB
    if (ws_size >= need) {
        unsigned short* W1F = (unsigned short*)d_ws;
        unsigned short* W2F = W1F + (size_t)256 * 1024;
        hipLaunchKernelGGL(gml_prep, dim3(512), dim3(256), 0, stream, W1, W2, W1F, W2F);
        hipLaunchKernelGGL(gml_main, dim3(MROWS / 64), dim3(512), 0, stream,
                           slots, b1, b2, gamma, beta, W1F, W2F, out);
    } else {
        hipLaunchKernelGGL(gml_naive, dim3(MROWS), dim3(256), 0, stream,
                           slots, W1, b1, W2, b2, gamma, beta, out);
    }
}